// Round 2
// baseline (237.963 us; speedup 1.0000x reference)
//
#include <hip/hip_runtime.h>
#include <stdint.h>

#define S_LEN 4096
#define DMODEL 512
#define NHEAD 8
#define DK 64
#define SPLIT 4
#define NT ((S_LEN / SPLIT) / 64)

typedef __attribute__((ext_vector_type(8))) short short8;
typedef __attribute__((ext_vector_type(4))) float f32x4;

__device__ __forceinline__ unsigned short f2bf(float f) {
    unsigned int u = __float_as_uint(f);
    u = (u + 0x7fffu + ((u >> 16) & 1u)) >> 16;
    return (unsigned short)u;
}

// ---------------- prep kernels ----------------

__global__ void cast_bf16_kernel(const float* __restrict__ in,
                                 unsigned short* __restrict__ out, int n4) {
    int i = blockIdx.x * blockDim.x + threadIdx.x;
    if (i >= n4) return;
    float4 v = reinterpret_cast<const float4*>(in)[i];
    ushort4 o;
    o.x = f2bf(v.x); o.y = f2bf(v.y); o.z = f2bf(v.z); o.w = f2bf(v.w);
    reinterpret_cast<ushort4*>(out)[i] = o;
}

// out[h][c][r] = in[h][r][c]  (bf16 transposed weights, BT layout)
__global__ void transpose_w_kernel(const float* __restrict__ in,
                                   unsigned short* __restrict__ out,
                                   int R, int C, int total) {
    int o = blockIdx.x * blockDim.x + threadIdx.x;
    if (o >= total) return;
    int h = o / (R * C);
    int rem = o - h * (R * C);
    int c = rem / R;
    int r = rem - c * R;
    out[o] = f2bf(in[h * R * C + r * C + c]);
}

__global__ void zero_kernel(float* z) { *z = 0.0f; }

// ---------------- QKV projection GEMM ----------------
// C[h][s][n] = sum_d emb[s][d] * W[h][d][n];  Q gets extra *0.125 (1/sqrt(64))
__global__ __launch_bounds__(256) void proj_gemm_kernel(
    const unsigned short* __restrict__ A,
    const unsigned short* __restrict__ WTq,
    const unsigned short* __restrict__ WTk,
    const unsigned short* __restrict__ WTv,
    unsigned short* __restrict__ Qo,
    unsigned short* __restrict__ Ko,
    unsigned short* __restrict__ Vo) {
    int tid = threadIdx.x;
    int w = tid >> 6, l = tid & 63;
    int l15 = l & 15, lg = l >> 4;
    int mb = blockIdx.x;
    int p = blockIdx.y >> 3, h = blockIdx.y & 7;
    const unsigned short* BT = (p == 0 ? WTq : p == 1 ? WTk : WTv) + h * (DK * DMODEL);
    unsigned short* C = (p == 0 ? Qo : p == 1 ? Ko : Vo) + h * (S_LEN * DK);
    float scale = (p == 0) ? 0.125f : 1.0f;
    int row_a = mb * 64 + w * 16 + l15;
    f32x4 acc[4] = {};
    for (int ks = 0; ks < DMODEL; ks += 32) {
        short8 a = *reinterpret_cast<const short8*>(A + row_a * DMODEL + ks + lg * 8);
#pragma unroll
        for (int nb = 0; nb < 4; ++nb) {
            short8 b = *reinterpret_cast<const short8*>(BT + (nb * 16 + l15) * DMODEL + ks + lg * 8);
            acc[nb] = __builtin_amdgcn_mfma_f32_16x16x32_bf16(a, b, acc[nb], 0, 0, 0);
        }
    }
    int row_c = mb * 64 + w * 16 + lg * 4;
#pragma unroll
    for (int nb = 0; nb < 4; ++nb)
#pragma unroll
        for (int r = 0; r < 4; ++r)
            C[(row_c + r) * DK + nb * 16 + l15] = f2bf(acc[nb][r] * scale);
}

// ---------------- fused attention (unnormalized, split over t) ----------------
// Opart[sp][h][q][v] = sum_{t in chunk sp} exp(S[q][t]) * V[t][v];  Z += sum exp
// 8 waves x 16 q-rows, t tiled by 64. K tile and V^T tile in LDS (XOR swizzle).
// Register prefetch of next tile's K/V overlaps global latency with compute.
__global__ __launch_bounds__(512) void attn_kernel(
    const unsigned short* __restrict__ Qg,
    const unsigned short* __restrict__ Kg,
    const unsigned short* __restrict__ Vg,
    float* __restrict__ Opart,
    float* __restrict__ Z) {
    __shared__ unsigned short lds[16384];  // K:[0,4096) Vt:[4096,8192) P: 8x1024
    int tid = threadIdx.x;
    int w = tid >> 6, l = tid & 63;
    int l15 = l & 15, lg = l >> 4;
    int qb = blockIdx.x, h = blockIdx.y, sp = blockIdx.z;
    const unsigned short* Qh = Qg + h * (S_LEN * DK);
    const unsigned short* Kh = Kg + h * (S_LEN * DK);
    const unsigned short* Vh = Vg + h * (S_LEN * DK);
    int t_base = sp * (S_LEN / SPLIT);
    int qr0 = qb * 128 + w * 16;
    short8 aq[2];
#pragma unroll
    for (int ks = 0; ks < 2; ++ks)
        aq[ks] = *reinterpret_cast<const short8*>(Qh + (qr0 + l15) * DK + ks * 32 + lg * 8);
    f32x4 o[4] = {};
    float zloc = 0.0f;
    unsigned short* Pw = lds + 8192 + w * 1024;  // [16][64] swizzled
    int kc_t = tid >> 3;        // K stage: row 0..63
    int kc_c8 = (tid & 7) * 8;  //          col chunk
    int vc_t = tid & 63;        // V stage: t 0..63
    int vc_vg = tid >> 6;       //          v group 0..7
    // prefetch tile 0 into registers
    short8 kreg = *reinterpret_cast<const short8*>(Kh + (t_base + kc_t) * DK + kc_c8);
    short8 vreg = *reinterpret_cast<const short8*>(Vh + (t_base + vc_t) * DK + vc_vg * 8);
    for (int it = 0; it < NT; ++it) {
        // write staged registers to LDS (prev iteration's compute done at loop-bottom barrier)
        *reinterpret_cast<short8*>(&lds[kc_t * 64 + (kc_c8 ^ ((kc_t & 7) << 3))]) = kreg;
#pragma unroll
        for (int i = 0; i < 8; ++i) {
            int v = vc_vg * 8 + i;
            lds[4096 + v * 64 + (vc_t ^ ((v & 7) << 3))] = (unsigned short)vreg[i];
        }
        __syncthreads();
        // issue next tile's global loads; latency hides under compute below
        if (it + 1 < NT) {
            int tn = t_base + (it + 1) * 64;
            kreg = *reinterpret_cast<const short8*>(Kh + (tn + kc_t) * DK + kc_c8);
            vreg = *reinterpret_cast<const short8*>(Vh + (tn + vc_t) * DK + vc_vg * 8);
        }
        // S = Q K^T (Q pre-scaled by 1/8)
        f32x4 sacc[4] = {};
#pragma unroll
        for (int ks = 0; ks < 2; ++ks) {
#pragma unroll
            for (int tb = 0; tb < 4; ++tb) {
                int t = tb * 16 + l15;
                short8 bk = *reinterpret_cast<const short8*>(
                    &lds[t * 64 + ((ks * 32 + lg * 8) ^ ((t & 7) << 3))]);
                sacc[tb] = __builtin_amdgcn_mfma_f32_16x16x32_bf16(aq[ks], bk, sacc[tb], 0, 0, 0);
            }
        }
        // exp, Z partial, P -> LDS (bf16)
#pragma unroll
        for (int tb = 0; tb < 4; ++tb) {
#pragma unroll
            for (int r = 0; r < 4; ++r) {
                float p = __expf(sacc[tb][r]);
                zloc += p;
                int ql = lg * 4 + r;
                int t = tb * 16 + l15;
                Pw[ql * 64 + (t ^ ((ql & 7) << 3))] = f2bf(p);
            }
        }
        // O += P V
#pragma unroll
        for (int ks2 = 0; ks2 < 2; ++ks2) {
            short8 pa = *reinterpret_cast<const short8*>(
                &Pw[l15 * 64 + ((ks2 * 32 + lg * 8) ^ ((l15 & 7) << 3))]);
#pragma unroll
            for (int vb = 0; vb < 4; ++vb) {
                int v = vb * 16 + l15;
                short8 bv = *reinterpret_cast<const short8*>(
                    &lds[4096 + v * 64 + ((ks2 * 32 + lg * 8) ^ ((v & 7) << 3))]);
                o[vb] = __builtin_amdgcn_mfma_f32_16x16x32_bf16(pa, bv, o[vb], 0, 0, 0);
            }
        }
        __syncthreads();
    }
    // write unnormalized f32 partials: Opart[sp][h][q][v]
    float* Op = Opart + ((size_t)(sp * NHEAD + h) * S_LEN) * DK;
#pragma unroll
    for (int vb = 0; vb < 4; ++vb)
#pragma unroll
        for (int r = 0; r < 4; ++r)
            Op[(qr0 + lg * 4 + r) * DK + vb * 16 + l15] = o[vb][r];
    // Z: wave reduce + one atomic per wave
#pragma unroll
    for (int off = 32; off > 0; off >>= 1)
        zloc += __shfl_xor(zloc, off, 64);
    if (l == 0) atomicAdd(Z, zloc);
}

// ---------------- split reduction: sum partials -> bf16 concat ----------------
__global__ __launch_bounds__(256) void reduce_o_kernel(
    const float* __restrict__ Opart, unsigned short* __restrict__ cc) {
    const int HSV = NHEAD * S_LEN * DK;  // 2M elements
    int i = blockIdx.x * blockDim.x + threadIdx.x;  // one f32x4 group
    if (i * 4 >= HSV) return;
    f32x4 s = {};
#pragma unroll
    for (int sp = 0; sp < SPLIT; ++sp) {
        f32x4 v = *reinterpret_cast<const f32x4*>(&Opart[(size_t)sp * HSV + i * 4]);
        s += v;
    }
    int e = i * 4;
    int h = e / (S_LEN * DK);
    int rem = e - h * (S_LEN * DK);
    int srow = rem / DK;
    int v = rem - srow * DK;
    ushort4 o4;
    o4.x = f2bf(s[0]); o4.y = f2bf(s[1]); o4.z = f2bf(s[2]); o4.w = f2bf(s[3]);
    *reinterpret_cast<ushort4*>(&cc[srow * DMODEL + h * DK + v]) = o4;
}

// ---------------- output projection GEMM (x 1/Z) ----------------
__global__ __launch_bounds__(256) void out_gemm_kernel(
    const unsigned short* __restrict__ A,   // concat bf16 [4096][512]
    const unsigned short* __restrict__ BT,  // woT bf16 [m][hv]
    const float* __restrict__ Z,
    float* __restrict__ Cout) {
    int tid = threadIdx.x;
    int w = tid >> 6, l = tid & 63;
    int l15 = l & 15, lg = l >> 4;
    int mb = blockIdx.x, nb0 = blockIdx.y * 64;
    float invZ = 1.0f / *Z;
    int row_a = mb * 64 + w * 16 + l15;
    f32x4 acc[4] = {};
    for (int ks = 0; ks < DMODEL; ks += 32) {
        short8 a = *reinterpret_cast<const short8*>(A + row_a * DMODEL + ks + lg * 8);
#pragma unroll
        for (int nb = 0; nb < 4; ++nb) {
            short8 b = *reinterpret_cast<const short8*>(BT + (nb0 + nb * 16 + l15) * DMODEL + ks + lg * 8);
            acc[nb] = __builtin_amdgcn_mfma_f32_16x16x32_bf16(a, b, acc[nb], 0, 0, 0);
        }
    }
    int row_c = mb * 64 + w * 16 + lg * 4;
#pragma unroll
    for (int nb = 0; nb < 4; ++nb)
#pragma unroll
        for (int r = 0; r < 4; ++r)
            Cout[(row_c + r) * DMODEL + nb0 + nb * 16 + l15] = acc[nb][r] * invZ;
}

// ---------------- launcher ----------------

extern "C" void kernel_launch(void* const* d_in, const int* in_sizes, int n_in,
                              void* d_out, int out_size, void* d_ws, size_t ws_size,
                              hipStream_t stream) {
    const float* emb = (const float*)d_in[0];
    const float* wq = (const float*)d_in[1];
    const float* wk = (const float*)d_in[2];
    const float* wv = (const float*)d_in[3];
    const float* wo = (const float*)d_in[4];
    float* out = (float*)d_out;
    char* ws = (char*)d_ws;
    unsigned short* embB = (unsigned short*)(ws);             // 4 MB
    unsigned short* wqT  = (unsigned short*)(ws + 4194304);   // 512 KB each
    unsigned short* wkT  = (unsigned short*)(ws + 4718592);
    unsigned short* wvT  = (unsigned short*)(ws + 5242880);
    unsigned short* woT  = (unsigned short*)(ws + 5767168);
    unsigned short* Qb   = (unsigned short*)(ws + 6291456);   // 4 MB each
    unsigned short* Kb   = (unsigned short*)(ws + 10485760);
    unsigned short* Vb   = (unsigned short*)(ws + 14680064);
    unsigned short* cc   = (unsigned short*)(ws + 18874368);  // 4 MB
    float* Z             = (float*)(ws + 23068672);
    float* Opart         = (float*)(ws + 23072768);           // 32 MB (4 x 8 MB)

    cast_bf16_kernel<<<2048, 256, 0, stream>>>(emb, embB, 524288);
    transpose_w_kernel<<<1024, 256, 0, stream>>>(wq, wqT, 512, 64, 262144);
    transpose_w_kernel<<<1024, 256, 0, stream>>>(wk, wkT, 512, 64, 262144);
    transpose_w_kernel<<<1024, 256, 0, stream>>>(wv, wvT, 512, 64, 262144);
    transpose_w_kernel<<<1024, 256, 0, stream>>>(wo, woT, 512, 512, 262144);
    zero_kernel<<<1, 1, 0, stream>>>(Z);
    proj_gemm_kernel<<<dim3(64, 24), 256, 0, stream>>>(embB, wqT, wkT, wvT, Qb, Kb, Vb);
    attn_kernel<<<dim3(32, 8, SPLIT), 512, 0, stream>>>(Qb, Kb, Vb, Opart, Z);
    reduce_o_kernel<<<2048, 256, 0, stream>>>(Opart, cc);
    out_gemm_kernel<<<dim3(64, 8), 256, 0, stream>>>(cc, woT, Z, out);
}

// Round 3
// 188.954 us; speedup vs baseline: 1.2594x; 1.2594x over previous
//
#include <hip/hip_runtime.h>
#include <stdint.h>

#define S_LEN 4096
#define DMODEL 512
#define NHEAD 8
#define DK 64
#define SPLIT 4
#define NT ((S_LEN / SPLIT) / 64)

typedef __attribute__((ext_vector_type(8))) short short8;
typedef __attribute__((ext_vector_type(4))) float f32x4;
typedef __attribute__((ext_vector_type(16))) float f32x16;

__device__ __forceinline__ unsigned short f2bf(float f) {
    unsigned int u = __float_as_uint(f);
    u = (u + 0x7fffu + ((u >> 16) & 1u)) >> 16;
    return (unsigned short)u;
}

// ---------------- prep kernels ----------------

__global__ void cast_bf16_kernel(const float* __restrict__ in,
                                 unsigned short* __restrict__ out, int n4,
                                 float* __restrict__ Z) {
    int i = blockIdx.x * blockDim.x + threadIdx.x;
    if (i == 0) *Z = 0.0f;
    if (i >= n4) return;
    float4 v = reinterpret_cast<const float4*>(in)[i];
    ushort4 o;
    o.x = f2bf(v.x); o.y = f2bf(v.y); o.z = f2bf(v.z); o.w = f2bf(v.w);
    reinterpret_cast<ushort4*>(out)[i] = o;
}

// out[h][c][r] = in[h][r][c]  (bf16 transposed weights, BT layout)
// blockIdx.y selects among q/k/v weight tensors
__global__ void transpose_wqkv_kernel(const float* __restrict__ wq,
                                      const float* __restrict__ wk,
                                      const float* __restrict__ wv,
                                      unsigned short* __restrict__ oq,
                                      unsigned short* __restrict__ ok,
                                      unsigned short* __restrict__ ov) {
    const int R = DMODEL, C = DK, total = NHEAD * R * C;
    int o = blockIdx.x * blockDim.x + threadIdx.x;
    if (o >= total) return;
    int p = blockIdx.y;
    const float* in = (p == 0) ? wq : (p == 1) ? wk : wv;
    unsigned short* out = (p == 0) ? oq : (p == 1) ? ok : ov;
    int h = o / (R * C);
    int rem = o - h * (R * C);
    int c = rem / R;
    int r = rem - c * R;
    out[o] = f2bf(in[h * R * C + r * C + c]);
}

__global__ void transpose_w_kernel(const float* __restrict__ in,
                                   unsigned short* __restrict__ out,
                                   int R, int C, int total) {
    int o = blockIdx.x * blockDim.x + threadIdx.x;
    if (o >= total) return;
    int h = o / (R * C);
    int rem = o - h * (R * C);
    int c = rem / R;
    int r = rem - c * R;
    out[o] = f2bf(in[h * R * C + r * C + c]);
}

// ---------------- QKV projection GEMM ----------------
__global__ __launch_bounds__(256) void proj_gemm_kernel(
    const unsigned short* __restrict__ A,
    const unsigned short* __restrict__ WTq,
    const unsigned short* __restrict__ WTk,
    const unsigned short* __restrict__ WTv,
    unsigned short* __restrict__ Qo,
    unsigned short* __restrict__ Ko,
    unsigned short* __restrict__ Vo) {
    int tid = threadIdx.x;
    int w = tid >> 6, l = tid & 63;
    int l15 = l & 15, lg = l >> 4;
    int mb = blockIdx.x;
    int p = blockIdx.y >> 3, h = blockIdx.y & 7;
    const unsigned short* BT = (p == 0 ? WTq : p == 1 ? WTk : WTv) + h * (DK * DMODEL);
    unsigned short* C = (p == 0 ? Qo : p == 1 ? Ko : Vo) + h * (S_LEN * DK);
    float scale = (p == 0) ? 0.125f : 1.0f;
    int row_a = mb * 64 + w * 16 + l15;
    f32x4 acc[4] = {};
    for (int ks = 0; ks < DMODEL; ks += 32) {
        short8 a = *reinterpret_cast<const short8*>(A + row_a * DMODEL + ks + lg * 8);
#pragma unroll
        for (int nb = 0; nb < 4; ++nb) {
            short8 b = *reinterpret_cast<const short8*>(BT + (nb * 16 + l15) * DMODEL + ks + lg * 8);
            acc[nb] = __builtin_amdgcn_mfma_f32_16x16x32_bf16(a, b, acc[nb], 0, 0, 0);
        }
    }
    int row_c = mb * 64 + w * 16 + lg * 4;
#pragma unroll
    for (int nb = 0; nb < 4; ++nb)
#pragma unroll
        for (int r = 0; r < 4; ++r)
            C[(row_c + r) * DK + nb * 16 + l15] = f2bf(acc[nb][r] * scale);
}

// ---------------- V transpose: Vb[h][t][v] -> VT[h][v][t] ----------------
__global__ __launch_bounds__(256) void vt_kernel(const unsigned short* __restrict__ Vb,
                                                 unsigned short* __restrict__ VT) {
    __shared__ unsigned short tile[4096];  // [64 t][64 v], XOR-swizzled by t row
    int h = blockIdx.y, t0 = blockIdx.x * 64;
    const unsigned short* Vh = Vb + h * (S_LEN * DK);
    unsigned short* VTh = VT + h * (DK * S_LEN);
    int c8 = (threadIdx.x & 7) * 8, rw = threadIdx.x >> 3;  // rw 0..31
#pragma unroll
    for (int rr = 0; rr < 2; ++rr) {
        int t = rw + rr * 32;
        short8 v = *reinterpret_cast<const short8*>(Vh + (t0 + t) * DK + c8);
        *reinterpret_cast<short8*>(&tile[t * 64 + (c8 ^ ((t & 7) << 3))]) = v;
    }
    __syncthreads();
#pragma unroll
    for (int rr = 0; rr < 2; ++rr) {
        int v = rw + rr * 32;
        short8 s;
#pragma unroll
        for (int i = 0; i < 8; ++i) {
            int t = c8 + i;
            s[i] = (short)tile[t * 64 + (v ^ ((t & 7) << 3))];
        }
        *reinterpret_cast<short8*>(VTh + v * S_LEN + t0 + c8) = s;
    }
}

// ---------------- fused attention (unnormalized, split over t) ----------------
// 32x32x16 MFMA. Per block: 4 waves x 32 q-rows = 128 q. t tiled by 64.
// Swapped QK^T (S^T = mfma(K,Q)) so P stores are packed b64 writes.
__global__ __launch_bounds__(256, 4) void attn_kernel(
    const unsigned short* __restrict__ Qg,
    const unsigned short* __restrict__ Kg,
    const unsigned short* __restrict__ VTg,
    float* __restrict__ Opart,
    float* __restrict__ Z) {
    __shared__ unsigned short lds[16384];  // K [64][64] @0, VT [64][64] @4096, P 4x[32][64] @8192
    int tid = threadIdx.x;
    int w = tid >> 6, l = tid & 63;
    int l31 = l & 31, lh = l >> 5;
    int qb = blockIdx.x, h = blockIdx.y, sp = blockIdx.z;
    const unsigned short* Qh = Qg + h * (S_LEN * DK);
    const unsigned short* Kh = Kg + h * (S_LEN * DK);
    const unsigned short* VTh = VTg + h * (DK * S_LEN);
    int t_base = sp * (S_LEN / SPLIT);
    int q0 = qb * 128 + w * 32;
    // Q B-fragments (held in registers): lane holds Q[q0+l31][ks*16 + lh*8 .. +7]
    short8 bq[4];
#pragma unroll
    for (int ks = 0; ks < 4; ++ks)
        bq[ks] = *reinterpret_cast<const short8*>(Qh + (q0 + l31) * DK + ks * 16 + lh * 8);
    f32x16 oacc[2] = {};
    float zloc = 0.0f;
    unsigned short* Pw = &lds[8192 + w * 2048];  // [32 q][64 t] swizzled
    int st_r = tid >> 3;          // staging row 0..31 (+32)
    int st_c8 = (tid & 7) * 8;    // staging col chunk
    // prefetch tile 0
    short8 kreg[2], vreg[2];
#pragma unroll
    for (int rr = 0; rr < 2; ++rr) {
        kreg[rr] = *reinterpret_cast<const short8*>(Kh + (t_base + st_r + rr * 32) * DK + st_c8);
        vreg[rr] = *reinterpret_cast<const short8*>(VTh + (st_r + rr * 32) * S_LEN + t_base + st_c8);
    }
    for (int it = 0; it < NT; ++it) {
        // write staged regs to LDS (prev tile's reads completed at loop-bottom barrier)
#pragma unroll
        for (int rr = 0; rr < 2; ++rr) {
            int tr = st_r + rr * 32;
            int sc = st_c8 ^ ((tr & 7) << 3);
            *reinterpret_cast<short8*>(&lds[tr * 64 + sc]) = kreg[rr];
            *reinterpret_cast<short8*>(&lds[4096 + tr * 64 + sc]) = vreg[rr];
        }
        __syncthreads();
        // issue next tile's global loads (latency hides under compute)
        if (it + 1 < NT) {
            int tn = t_base + (it + 1) * 64;
#pragma unroll
            for (int rr = 0; rr < 2; ++rr) {
                kreg[rr] = *reinterpret_cast<const short8*>(Kh + (tn + st_r + rr * 32) * DK + st_c8);
                vreg[rr] = *reinterpret_cast<const short8*>(VTh + (st_r + rr * 32) * S_LEN + tn + st_c8);
            }
        }
        // S^T[t][q] = sum_k K[t][k] Q[q][k]
        f32x16 sacc[2] = {};
#pragma unroll
        for (int ks = 0; ks < 4; ++ks) {
#pragma unroll
            for (int tc = 0; tc < 2; ++tc) {
                int t = tc * 32 + l31;
                short8 ka = *reinterpret_cast<const short8*>(
                    &lds[t * 64 + ((ks * 16 + lh * 8) ^ ((t & 7) << 3))]);
                sacc[tc] = __builtin_amdgcn_mfma_f32_32x32x16_bf16(ka, bq[ks], sacc[tc], 0, 0, 0);
            }
        }
        // exp -> packed bf16 P[q][t] (4 consecutive t per reg group -> b64 writes)
#pragma unroll
        for (int tc = 0; tc < 2; ++tc) {
#pragma unroll
            for (int g = 0; g < 4; ++g) {
                float p0 = __expf(sacc[tc][4 * g + 0]);
                float p1 = __expf(sacc[tc][4 * g + 1]);
                float p2 = __expf(sacc[tc][4 * g + 2]);
                float p3 = __expf(sacc[tc][4 * g + 3]);
                zloc += (p0 + p1) + (p2 + p3);
                unsigned int lo = (unsigned int)f2bf(p0) | ((unsigned int)f2bf(p1) << 16);
                unsigned int hi = (unsigned int)f2bf(p2) | ((unsigned int)f2bf(p3) << 16);
                unsigned long long pk = (unsigned long long)lo | ((unsigned long long)hi << 32);
                int tb = tc * 32 + g * 8 + lh * 4;
                *reinterpret_cast<unsigned long long*>(
                    &Pw[l31 * 64 + (tb ^ ((l31 & 7) << 3))]) = pk;
            }
        }
        // O[q][v] += P[q][t] VT[v][t]
#pragma unroll
        for (int ts = 0; ts < 4; ++ts) {
            short8 pa = *reinterpret_cast<const short8*>(
                &Pw[l31 * 64 + ((ts * 16 + lh * 8) ^ ((l31 & 7) << 3))]);
#pragma unroll
            for (int vc = 0; vc < 2; ++vc) {
                int v = vc * 32 + l31;
                short8 bv = *reinterpret_cast<const short8*>(
                    &lds[4096 + v * 64 + ((ts * 16 + lh * 8) ^ ((v & 7) << 3))]);
                oacc[vc] = __builtin_amdgcn_mfma_f32_32x32x16_bf16(pa, bv, oacc[vc], 0, 0, 0);
            }
        }
        __syncthreads();
    }
    // write f32 partials: Opart[sp][h][q][v]
    float* Op = Opart + ((size_t)(sp * NHEAD + h) * S_LEN + q0) * DK;
#pragma unroll
    for (int vc = 0; vc < 2; ++vc)
#pragma unroll
        for (int reg = 0; reg < 16; ++reg) {
            int q = (reg & 3) + 8 * (reg >> 2) + 4 * lh;
            Op[q * DK + vc * 32 + l31] = oacc[vc][reg];
        }
    // Z: wave reduce + one atomic per wave
#pragma unroll
    for (int off = 32; off > 0; off >>= 1)
        zloc += __shfl_xor(zloc, off, 64);
    if (l == 0) atomicAdd(Z, zloc);
}

// ---------------- split reduction: sum partials -> bf16 concat ----------------
__global__ __launch_bounds__(256) void reduce_o_kernel(
    const float* __restrict__ Opart, unsigned short* __restrict__ cc) {
    const int HSV = NHEAD * S_LEN * DK;  // 2M elements
    int i = blockIdx.x * blockDim.x + threadIdx.x;
    if (i * 4 >= HSV) return;
    f32x4 s = {};
#pragma unroll
    for (int sp = 0; sp < SPLIT; ++sp) {
        f32x4 v = *reinterpret_cast<const f32x4*>(&Opart[(size_t)sp * HSV + i * 4]);
        s += v;
    }
    int e = i * 4;
    int h = e / (S_LEN * DK);
    int rem = e - h * (S_LEN * DK);
    int srow = rem / DK;
    int v = rem - srow * DK;
    ushort4 o4;
    o4.x = f2bf(s[0]); o4.y = f2bf(s[1]); o4.z = f2bf(s[2]); o4.w = f2bf(s[3]);
    *reinterpret_cast<ushort4*>(&cc[srow * DMODEL + h * DK + v]) = o4;
}

// ---------------- output projection GEMM (x 1/Z) ----------------
__global__ __launch_bounds__(256) void out_gemm_kernel(
    const unsigned short* __restrict__ A,
    const unsigned short* __restrict__ BT,
    const float* __restrict__ Z,
    float* __restrict__ Cout) {
    int tid = threadIdx.x;
    int w = tid >> 6, l = tid & 63;
    int l15 = l & 15, lg = l >> 4;
    int mb = blockIdx.x, nb0 = blockIdx.y * 64;
    float invZ = 1.0f / *Z;
    int row_a = mb * 64 + w * 16 + l15;
    f32x4 acc[4] = {};
    for (int ks = 0; ks < DMODEL; ks += 32) {
        short8 a = *reinterpret_cast<const short8*>(A + row_a * DMODEL + ks + lg * 8);
#pragma unroll
        for (int nb = 0; nb < 4; ++nb) {
            short8 b = *reinterpret_cast<const short8*>(BT + (nb0 + nb * 16 + l15) * DMODEL + ks + lg * 8);
            acc[nb] = __builtin_amdgcn_mfma_f32_16x16x32_bf16(a, b, acc[nb], 0, 0, 0);
        }
    }
    int row_c = mb * 64 + w * 16 + lg * 4;
#pragma unroll
    for (int nb = 0; nb < 4; ++nb)
#pragma unroll
        for (int r = 0; r < 4; ++r)
            Cout[(row_c + r) * DMODEL + nb0 + nb * 16 + l15] = acc[nb][r] * invZ;
}

// ---------------- launcher ----------------

extern "C" void kernel_launch(void* const* d_in, const int* in_sizes, int n_in,
                              void* d_out, int out_size, void* d_ws, size_t ws_size,
                              hipStream_t stream) {
    const float* emb = (const float*)d_in[0];
    const float* wq = (const float*)d_in[1];
    const float* wk = (const float*)d_in[2];
    const float* wv = (const float*)d_in[3];
    const float* wo = (const float*)d_in[4];
    float* out = (float*)d_out;
    char* ws = (char*)d_ws;
    unsigned short* embB = (unsigned short*)(ws);             // 4 MB (reused as VT after proj)
    unsigned short* wqT  = (unsigned short*)(ws + 4194304);
    unsigned short* wkT  = (unsigned short*)(ws + 4718592);
    unsigned short* wvT  = (unsigned short*)(ws + 5242880);
    unsigned short* woT  = (unsigned short*)(ws + 5767168);
    unsigned short* Qb   = (unsigned short*)(ws + 6291456);   // 4 MB each
    unsigned short* Kb   = (unsigned short*)(ws + 10485760);
    unsigned short* Vb   = (unsigned short*)(ws + 14680064);
    unsigned short* cc   = (unsigned short*)(ws + 18874368);  // 4 MB
    float* Z             = (float*)(ws + 23068672);
    float* Opart         = (float*)(ws + 23072768);           // 32 MB
    unsigned short* VT   = embB;  // reuse: embB dead after proj_gemm

    cast_bf16_kernel<<<2048, 256, 0, stream>>>(emb, embB, 524288, Z);
    transpose_wqkv_kernel<<<dim3(1024, 3), 256, 0, stream>>>(wq, wk, wv, wqT, wkT, wvT);
    transpose_w_kernel<<<1024, 256, 0, stream>>>(wo, woT, 512, 512, 262144);
    proj_gemm_kernel<<<dim3(64, 24), 256, 0, stream>>>(embB, wqT, wkT, wvT, Qb, Kb, Vb);
    vt_kernel<<<dim3(64, 8), 256, 0, stream>>>(Vb, VT);
    attn_kernel<<<dim3(32, 8, SPLIT), 256, 0, stream>>>(Qb, Kb, VT, Opart, Z);
    reduce_o_kernel<<<2048, 256, 0, stream>>>(Opart, cc);
    out_gemm_kernel<<<dim3(64, 8), 256, 0, stream>>>(cc, woT, Z, out);
}

// Round 4
// 156.453 us; speedup vs baseline: 1.5210x; 1.2077x over previous
//
#include <hip/hip_runtime.h>
#include <stdint.h>

#define S_LEN 4096
#define DMODEL 512
#define NHEAD 8
#define DK 64
#define SPLIT 4
#define NT ((S_LEN / SPLIT) / 64)

typedef __attribute__((ext_vector_type(8))) short short8;
typedef __attribute__((ext_vector_type(4))) float f32x4;
typedef __attribute__((ext_vector_type(16))) float f32x16;
typedef __attribute__((ext_vector_type(4))) unsigned int uint4v;
typedef __attribute__((ext_vector_type(2))) unsigned long long ull2;

__device__ __forceinline__ unsigned short f2bf(float f) {
    unsigned int u = __float_as_uint(f);
    u = (u + 0x7fffu + ((u >> 16) & 1u)) >> 16;
    return (unsigned short)u;
}

// async global->LDS, 16B per lane; LDS dest = wave-uniform base + lane*16
__device__ __forceinline__ void gload16(const unsigned short* g, unsigned short* l) {
    __builtin_amdgcn_global_load_lds(
        (const __attribute__((address_space(1))) unsigned int*)g,
        (__attribute__((address_space(3))) unsigned int*)l, 16, 0, 0);
}

// ---------------- prep kernels ----------------

__global__ void cast_bf16_kernel(const float* __restrict__ in,
                                 unsigned short* __restrict__ out, int n4,
                                 float* __restrict__ Z) {
    int i = blockIdx.x * blockDim.x + threadIdx.x;
    if (i == 0) *Z = 0.0f;
    if (i >= n4) return;
    float4 v = reinterpret_cast<const float4*>(in)[i];
    ushort4 o;
    o.x = f2bf(v.x); o.y = f2bf(v.y); o.z = f2bf(v.z); o.w = f2bf(v.w);
    reinterpret_cast<ushort4*>(out)[i] = o;
}

// LDS-tiled transpose+cast: in f32 [h][512][64] -> out bf16 [h][64][512]
// grid (8 r-tiles, 24 = p*8+h)
__global__ __launch_bounds__(256) void transpose_qkv_kernel(
    const float* __restrict__ wq, const float* __restrict__ wk, const float* __restrict__ wv,
    unsigned short* __restrict__ oq, unsigned short* __restrict__ ok, unsigned short* __restrict__ ov) {
    __shared__ float tile[64][65];
    const int p = blockIdx.y >> 3, h = blockIdx.y & 7;
    const int r0 = blockIdx.x * 64;
    const float* in = ((p == 0) ? wq : (p == 1) ? wk : wv) + (size_t)h * DMODEL * DK;
    unsigned short* out = ((p == 0) ? oq : (p == 1) ? ok : ov) + (size_t)h * DK * DMODEL;
    const int tr = threadIdx.x >> 4, tc4 = (threadIdx.x & 15) * 4;
#pragma unroll
    for (int rr = 0; rr < 4; ++rr) {
        float4 v = *reinterpret_cast<const float4*>(in + (size_t)(r0 + tr + rr * 16) * DK + tc4);
        tile[tr + rr * 16][tc4 + 0] = v.x;
        tile[tr + rr * 16][tc4 + 1] = v.y;
        tile[tr + rr * 16][tc4 + 2] = v.z;
        tile[tr + rr * 16][tc4 + 3] = v.w;
    }
    __syncthreads();
#pragma unroll
    for (int rr = 0; rr < 4; ++rr) {
        const int c = tr + rr * 16;
        ushort4 o;
        o.x = f2bf(tile[tc4 + 0][c]);
        o.y = f2bf(tile[tc4 + 1][c]);
        o.z = f2bf(tile[tc4 + 2][c]);
        o.w = f2bf(tile[tc4 + 3][c]);
        *reinterpret_cast<ushort4*>(out + (size_t)c * DMODEL + r0 + tc4) = o;
    }
}

// wo: f32 [512][512] -> bf16 [512][512] transposed; grid (8 c-tiles, 8 r-tiles)
__global__ __launch_bounds__(256) void transpose_wo_kernel(
    const float* __restrict__ in, unsigned short* __restrict__ out) {
    __shared__ float tile[64][65];
    const int c0 = blockIdx.x * 64, r0 = blockIdx.y * 64;
    const int tr = threadIdx.x >> 4, tc4 = (threadIdx.x & 15) * 4;
#pragma unroll
    for (int rr = 0; rr < 4; ++rr) {
        float4 v = *reinterpret_cast<const float4*>(in + (size_t)(r0 + tr + rr * 16) * DMODEL + c0 + tc4);
        tile[tr + rr * 16][tc4 + 0] = v.x;
        tile[tr + rr * 16][tc4 + 1] = v.y;
        tile[tr + rr * 16][tc4 + 2] = v.z;
        tile[tr + rr * 16][tc4 + 3] = v.w;
    }
    __syncthreads();
#pragma unroll
    for (int rr = 0; rr < 4; ++rr) {
        const int c = tr + rr * 16;
        ushort4 o;
        o.x = f2bf(tile[tc4 + 0][c]);
        o.y = f2bf(tile[tc4 + 1][c]);
        o.z = f2bf(tile[tc4 + 2][c]);
        o.w = f2bf(tile[tc4 + 3][c]);
        *reinterpret_cast<ushort4*>(out + (size_t)(c0 + c) * DMODEL + r0 + tc4) = o;
    }
}

// ---------------- QKV projection GEMM ----------------
__global__ __launch_bounds__(256) void proj_gemm_kernel(
    const unsigned short* __restrict__ A,
    const unsigned short* __restrict__ WTq,
    const unsigned short* __restrict__ WTk,
    const unsigned short* __restrict__ WTv,
    unsigned short* __restrict__ Qo,
    unsigned short* __restrict__ Ko,
    unsigned short* __restrict__ Vo) {
    int tid = threadIdx.x;
    int w = tid >> 6, l = tid & 63;
    int l15 = l & 15, lg = l >> 4;
    int mb = blockIdx.x;
    int p = blockIdx.y >> 3, h = blockIdx.y & 7;
    const unsigned short* BT = (p == 0 ? WTq : p == 1 ? WTk : WTv) + h * (DK * DMODEL);
    unsigned short* C = (p == 0 ? Qo : p == 1 ? Ko : Vo) + h * (S_LEN * DK);
    float scale = (p == 0) ? 0.125f : 1.0f;  // 1/sqrt(64) folded into Q
    int row_a = mb * 64 + w * 16 + l15;
    f32x4 acc[4] = {};
    for (int ks = 0; ks < DMODEL; ks += 32) {
        short8 a = *reinterpret_cast<const short8*>(A + row_a * DMODEL + ks + lg * 8);
#pragma unroll
        for (int nb = 0; nb < 4; ++nb) {
            short8 b = *reinterpret_cast<const short8*>(BT + (nb * 16 + l15) * DMODEL + ks + lg * 8);
            acc[nb] = __builtin_amdgcn_mfma_f32_16x16x32_bf16(a, b, acc[nb], 0, 0, 0);
        }
    }
    int row_c = mb * 64 + w * 16 + lg * 4;
#pragma unroll
    for (int nb = 0; nb < 4; ++nb)
#pragma unroll
        for (int r = 0; r < 4; ++r)
            C[(row_c + r) * DK + nb * 16 + l15] = f2bf(acc[nb][r] * scale);
}

// ---------------- V transpose: Vb[h][t][v] -> VT[h][v][t] ----------------
__global__ __launch_bounds__(256) void vt_kernel(const unsigned short* __restrict__ Vb,
                                                 unsigned short* __restrict__ VT) {
    __shared__ unsigned short tile[4096];
    int h = blockIdx.y, t0 = blockIdx.x * 64;
    const unsigned short* Vh = Vb + h * (S_LEN * DK);
    unsigned short* VTh = VT + h * (DK * S_LEN);
    int c8 = (threadIdx.x & 7) * 8, rw = threadIdx.x >> 3;
#pragma unroll
    for (int rr = 0; rr < 2; ++rr) {
        int t = rw + rr * 32;
        short8 v = *reinterpret_cast<const short8*>(Vh + (t0 + t) * DK + c8);
        *reinterpret_cast<short8*>(&tile[t * 64 + (c8 ^ ((t & 7) << 3))]) = v;
    }
    __syncthreads();
#pragma unroll
    for (int rr = 0; rr < 2; ++rr) {
        int v = rw + rr * 32;
        short8 s;
#pragma unroll
        for (int i = 0; i < 8; ++i) {
            int t = c8 + i;
            s[i] = (short)tile[t * 64 + (v ^ ((t & 7) << 3))];
        }
        *reinterpret_cast<short8*>(VTh + v * S_LEN + t0 + c8) = s;
    }
}

// ---------------- fused attention (unnormalized, split over t) ----------------
// 4 waves x 64 q-rows = 256 q per block. Swapped QK^T -> lane-local P rows;
// P stays in registers (cvt_pk packs, k-permuted PV with matching ds_read_b64
// VT fragments). K/VT staged via global_load_lds, double-buffered, swizzled.
__device__ __forceinline__ void make_pfrag(const f32x16& s, short8 pf[2],
                                           float& z0, float& z1) {
    float p[16];
#pragma unroll
    for (int r = 0; r < 16; ++r) p[r] = __expf(s[r]);
#pragma unroll
    for (int r = 0; r < 16; r += 2) { z0 += p[r]; z1 += p[r + 1]; }
    unsigned int c[8];
#pragma unroll
    for (int j = 0; j < 8; ++j)
        asm("v_cvt_pk_bf16_f32 %0, %1, %2" : "=v"(c[j]) : "v"(p[2 * j]), "v"(p[2 * j + 1]));
    uint4v wa = {c[0], c[1], c[2], c[3]};
    uint4v wb = {c[4], c[5], c[6], c[7]};
    pf[0] = __builtin_bit_cast(short8, wa);
    pf[1] = __builtin_bit_cast(short8, wb);
}

__global__ __launch_bounds__(256, 2) void attn_kernel(
    const unsigned short* __restrict__ Qg,
    const unsigned short* __restrict__ Kg,
    const unsigned short* __restrict__ VTg,
    float* __restrict__ Opart,
    float* __restrict__ Z) {
    __shared__ unsigned short lds[16384];  // 2 bufs x (K[64][64] + VT[64][64]), XOR-swizzled
    const int tid = threadIdx.x;
    const int w = tid >> 6, l = tid & 63;
    const int l31 = l & 31, lh = l >> 5;
    const int qb = blockIdx.x, h = blockIdx.y, sp = blockIdx.z;
    const unsigned short* Qh = Qg + h * (S_LEN * DK);
    const unsigned short* Kh = Kg + h * (S_LEN * DK);
    const unsigned short* VTh = VTg + h * (DK * S_LEN);
    const int t_base = sp * (S_LEN / SPLIT);
    const int q0 = qb * 256 + w * 64;

    // Q B-fragments in registers: bq[qc][ks] = Q[q0+qc*32+l31][ks*16+lh*8 ..+7]
    short8 bq[2][4];
#pragma unroll
    for (int qc = 0; qc < 2; ++qc)
#pragma unroll
        for (int ks = 0; ks < 4; ++ks)
            bq[qc][ks] = *reinterpret_cast<const short8*>(
                Qh + (q0 + qc * 32 + l31) * DK + ks * 16 + lh * 8);

    f32x16 oacc[2][2] = {};  // [qc][vc]
    float z0 = 0.0f, z1 = 0.0f;

    // staging: pre-swizzled global source, linear LDS dest (rule: both-sides)
    const int srow = l >> 3;                  // row within 8-row group
    const int scol = ((l & 7) ^ srow) << 3;   // pre-swizzled col chunk (elements)
    const unsigned short* gk = Kh + (size_t)(t_base + w * 16 + srow) * DK + scol;
    const unsigned short* gv0 = VTh + (size_t)(w * 16 + srow) * S_LEN + t_base + scol;
    const unsigned short* gv1 = gv0 + 8 * S_LEN;

    {   // stage tile 0 -> buf 0
        unsigned short* kb = &lds[w * 1024];
        gload16(gk, kb);
        gload16(gk + 512, kb + 512);
        unsigned short* vb = &lds[4096 + w * 1024];
        gload16(gv0, vb);
        gload16(gv1, vb + 512);
        gk += 64 * DK; gv0 += 64; gv1 += 64;
    }
    __syncthreads();  // compiler drains vmcnt before s_barrier

    for (int it = 0; it < NT; ++it) {
        const int b = (it & 1) * 8192;
        if (it + 1 < NT) {  // issue next tile's async loads; they drain at loop-end barrier
            const int nb = ((it + 1) & 1) * 8192;
            unsigned short* kb = &lds[nb + w * 1024];
            gload16(gk, kb);
            gload16(gk + 512, kb + 512);
            unsigned short* vb = &lds[nb + 4096 + w * 1024];
            gload16(gv0, vb);
            gload16(gv1, vb + 512);
            gk += 64 * DK; gv0 += 64; gv1 += 64;
        }
#pragma unroll
        for (int tc = 0; tc < 2; ++tc) {
            // S^T = K Q^T : lane holds S^T[t-rows][q = qc*32+l31]
            f32x16 s0 = {}, s1 = {};
#pragma unroll
            for (int ks = 0; ks < 4; ++ks) {
                const int tA = tc * 32 + l31;
                short8 ka = *reinterpret_cast<const short8*>(
                    &lds[b + tA * 64 + ((ks * 16 + lh * 8) ^ ((l31 & 7) << 3))]);
                s0 = __builtin_amdgcn_mfma_f32_32x32x16_bf16(ka, bq[0][ks], s0, 0, 0, 0);
                s1 = __builtin_amdgcn_mfma_f32_32x32x16_bf16(ka, bq[1][ks], s1, 0, 0, 0);
            }
            // exp -> bf16 A-fragments fully in-register (k-permuted order)
            short8 pf0[2], pf1[2];
            make_pfrag(s0, pf0, z0, z1);
            make_pfrag(s1, pf1, z0, z1);
            // PV: B-frags read as 2x ds_read_b64 in the SAME k-permuted t-order
#pragma unroll
            for (int sub = 0; sub < 2; ++sub) {
#pragma unroll
                for (int vc = 0; vc < 2; ++vc) {
                    const int vx = l31 & 7;
                    const int cc = tc * 4 + sub * 2;
                    const int base = b + 4096 + (vc * 32 + l31) * 64;
                    unsigned long long d0 = *reinterpret_cast<const unsigned long long*>(
                        &lds[base + ((cc ^ vx) << 3) + lh * 4]);
                    unsigned long long d1 = *reinterpret_cast<const unsigned long long*>(
                        &lds[base + (((cc + 1) ^ vx) << 3) + lh * 4]);
                    ull2 dd = {d0, d1};
                    short8 bv = __builtin_bit_cast(short8, dd);
                    oacc[0][vc] = __builtin_amdgcn_mfma_f32_32x32x16_bf16(pf0[sub], bv, oacc[0][vc], 0, 0, 0);
                    oacc[1][vc] = __builtin_amdgcn_mfma_f32_32x32x16_bf16(pf1[sub], bv, oacc[1][vc], 0, 0, 0);
                }
            }
        }
        __syncthreads();
    }
    // f32 partials: Opart[sp][h][q][v], coalesced (lanes = consecutive v)
    float* Op = Opart + ((size_t)(sp * NHEAD + h) * S_LEN + q0) * DK;
#pragma unroll
    for (int qc = 0; qc < 2; ++qc)
#pragma unroll
        for (int vc = 0; vc < 2; ++vc)
#pragma unroll
            for (int reg = 0; reg < 16; ++reg) {
                int q = qc * 32 + (reg & 3) + 8 * (reg >> 2) + 4 * lh;
                Op[(size_t)q * DK + vc * 32 + l31] = oacc[qc][vc][reg];
            }
    float zloc = z0 + z1;
#pragma unroll
    for (int off = 32; off > 0; off >>= 1) zloc += __shfl_xor(zloc, off, 64);
    if (l == 0) atomicAdd(Z, zloc);
}

// ---------------- split reduction: sum partials -> bf16 concat ----------------
__global__ __launch_bounds__(256) void reduce_o_kernel(
    const float* __restrict__ Opart, unsigned short* __restrict__ cc) {
    const int HSV = NHEAD * S_LEN * DK;
    int i = blockIdx.x * blockDim.x + threadIdx.x;
    if (i * 4 >= HSV) return;
    f32x4 s = {};
#pragma unroll
    for (int sp = 0; sp < SPLIT; ++sp) {
        f32x4 v = *reinterpret_cast<const f32x4*>(&Opart[(size_t)sp * HSV + i * 4]);
        s += v;
    }
    int e = i * 4;
    int h = e / (S_LEN * DK);
    int rem = e - h * (S_LEN * DK);
    int srow = rem / DK;
    int v = rem - srow * DK;
    ushort4 o4;
    o4.x = f2bf(s[0]); o4.y = f2bf(s[1]); o4.z = f2bf(s[2]); o4.w = f2bf(s[3]);
    *reinterpret_cast<ushort4*>(&cc[srow * DMODEL + h * DK + v]) = o4;
}

// ---------------- output projection GEMM (x 1/Z) ----------------
__global__ __launch_bounds__(256) void out_gemm_kernel(
    const unsigned short* __restrict__ A,
    const unsigned short* __restrict__ BT,
    const float* __restrict__ Z,
    float* __restrict__ Cout) {
    int tid = threadIdx.x;
    int w = tid >> 6, l = tid & 63;
    int l15 = l & 15, lg = l >> 4;
    int mb = blockIdx.x, nb0 = blockIdx.y * 64;
    float invZ = 1.0f / *Z;
    int row_a = mb * 64 + w * 16 + l15;
    f32x4 acc[4] = {};
    for (int ks = 0; ks < DMODEL; ks += 32) {
        short8 a = *reinterpret_cast<const short8*>(A + row_a * DMODEL + ks + lg * 8);
#pragma unroll
        for (int nb = 0; nb < 4; ++nb) {
            short8 b = *reinterpret_cast<const short8*>(BT + (nb0 + nb * 16 + l15) * DMODEL + ks + lg * 8);
            acc[nb] = __builtin_amdgcn_mfma_f32_16x16x32_bf16(a, b, acc[nb], 0, 0, 0);
        }
    }
    int row_c = mb * 64 + w * 16 + lg * 4;
#pragma unroll
    for (int nb = 0; nb < 4; ++nb)
#pragma unroll
        for (int r = 0; r < 4; ++r)
            Cout[(row_c + r) * DMODEL + nb0 + nb * 16 + l15] = acc[nb][r] * invZ;
}

// ---------------- launcher ----------------

extern "C" void kernel_launch(void* const* d_in, const int* in_sizes, int n_in,
                              void* d_out, int out_size, void* d_ws, size_t ws_size,
                              hipStream_t stream) {
    const float* emb = (const float*)d_in[0];
    const float* wq = (const float*)d_in[1];
    const float* wk = (const float*)d_in[2];
    const float* wv = (const float*)d_in[3];
    const float* wo = (const float*)d_in[4];
    float* out = (float*)d_out;
    char* ws = (char*)d_ws;
    unsigned short* embB = (unsigned short*)(ws);             // 4 MB (reused as VT)
    unsigned short* wqT  = (unsigned short*)(ws + 4194304);
    unsigned short* wkT  = (unsigned short*)(ws + 4718592);
    unsigned short* wvT  = (unsigned short*)(ws + 5242880);
    unsigned short* woT  = (unsigned short*)(ws + 5767168);
    unsigned short* Qb   = (unsigned short*)(ws + 6291456);   // 4 MB each
    unsigned short* Kb   = (unsigned short*)(ws + 10485760);
    unsigned short* Vb   = (unsigned short*)(ws + 14680064);
    unsigned short* cc   = (unsigned short*)(ws + 18874368);  // 4 MB
    float* Z             = (float*)(ws + 23068672);
    float* Opart         = (float*)(ws + 23072768);           // 32 MB
    unsigned short* VT   = embB;  // embB dead after proj_gemm

    cast_bf16_kernel<<<2048, 256, 0, stream>>>(emb, embB, 524288, Z);
    transpose_qkv_kernel<<<dim3(8, 24), 256, 0, stream>>>(wq, wk, wv, wqT, wkT, wvT);
    transpose_wo_kernel<<<dim3(8, 8), 256, 0, stream>>>(wo, woT);
    proj_gemm_kernel<<<dim3(64, 24), 256, 0, stream>>>(embB, wqT, wkT, wvT, Qb, Kb, Vb);
    vt_kernel<<<dim3(64, 8), 256, 0, stream>>>(Vb, VT);
    attn_kernel<<<dim3(16, 8, SPLIT), 256, 0, stream>>>(Qb, Kb, VT, Opart, Z);
    reduce_o_kernel<<<2048, 256, 0, stream>>>(Opart, cc);
    out_gemm_kernel<<<dim3(64, 8), 256, 0, stream>>>(cc, woT, Z, out);
}

// Round 5
// 102.968 us; speedup vs baseline: 2.3110x; 1.5194x over previous
//
#include <hip/hip_runtime.h>
#include <stdint.h>

#define S_LEN 4096
#define DMODEL 512
#define NHEAD 8
#define DK 64
#define SPLIT 4
#define TBLK 128
#define NT ((S_LEN / SPLIT) / TBLK)  // 8

typedef __attribute__((ext_vector_type(8))) short short8;
typedef __attribute__((ext_vector_type(4))) float f32x4;
typedef __attribute__((ext_vector_type(16))) float f32x16;
typedef __attribute__((ext_vector_type(4))) unsigned int uint4v;
typedef __attribute__((ext_vector_type(2))) unsigned long long ull2;

__device__ __forceinline__ unsigned short f2bf(float f) {
    unsigned int u = __float_as_uint(f);
    u = (u + 0x7fffu + ((u >> 16) & 1u)) >> 16;
    return (unsigned short)u;
}

// async global->LDS, 16B/lane; LDS dest = wave-uniform base + lane*16
__device__ __forceinline__ void gload16(const unsigned short* g, unsigned short* l) {
    __builtin_amdgcn_global_load_lds(
        (const __attribute__((address_space(1))) unsigned int*)g,
        (__attribute__((address_space(3))) unsigned int*)l, 16, 0, 0);
}

// ---------------- prep kernels ----------------

__global__ void cast_bf16_kernel(const float* __restrict__ in,
                                 unsigned short* __restrict__ out, int n4,
                                 float* __restrict__ Z) {
    int i = blockIdx.x * blockDim.x + threadIdx.x;
    if (i == 0) *Z = 0.0f;
    if (i >= n4) return;
    float4 v = reinterpret_cast<const float4*>(in)[i];
    ushort4 o;
    o.x = f2bf(v.x); o.y = f2bf(v.y); o.z = f2bf(v.z); o.w = f2bf(v.w);
    reinterpret_cast<ushort4*>(out)[i] = o;
}

// LDS-tiled transpose+cast: in f32 [h][512][64] -> out bf16 [h][64][512]
__global__ __launch_bounds__(256) void transpose_qkv_kernel(
    const float* __restrict__ wq, const float* __restrict__ wk, const float* __restrict__ wv,
    unsigned short* __restrict__ oq, unsigned short* __restrict__ ok, unsigned short* __restrict__ ov) {
    __shared__ float tile[64][65];
    const int p = blockIdx.y >> 3, h = blockIdx.y & 7;
    const int r0 = blockIdx.x * 64;
    const float* in = ((p == 0) ? wq : (p == 1) ? wk : wv) + (size_t)h * DMODEL * DK;
    unsigned short* out = ((p == 0) ? oq : (p == 1) ? ok : ov) + (size_t)h * DK * DMODEL;
    const int tr = threadIdx.x >> 4, tc4 = (threadIdx.x & 15) * 4;
#pragma unroll
    for (int rr = 0; rr < 4; ++rr) {
        float4 v = *reinterpret_cast<const float4*>(in + (size_t)(r0 + tr + rr * 16) * DK + tc4);
        tile[tr + rr * 16][tc4 + 0] = v.x;
        tile[tr + rr * 16][tc4 + 1] = v.y;
        tile[tr + rr * 16][tc4 + 2] = v.z;
        tile[tr + rr * 16][tc4 + 3] = v.w;
    }
    __syncthreads();
#pragma unroll
    for (int rr = 0; rr < 4; ++rr) {
        const int c = tr + rr * 16;
        ushort4 o;
        o.x = f2bf(tile[tc4 + 0][c]);
        o.y = f2bf(tile[tc4 + 1][c]);
        o.z = f2bf(tile[tc4 + 2][c]);
        o.w = f2bf(tile[tc4 + 3][c]);
        *reinterpret_cast<ushort4*>(out + (size_t)c * DMODEL + r0 + tc4) = o;
    }
}

// wo: f32 [512][512] -> bf16 transposed [512][512]
__global__ __launch_bounds__(256) void transpose_wo_kernel(
    const float* __restrict__ in, unsigned short* __restrict__ out) {
    __shared__ float tile[64][65];
    const int c0 = blockIdx.x * 64, r0 = blockIdx.y * 64;
    const int tr = threadIdx.x >> 4, tc4 = (threadIdx.x & 15) * 4;
#pragma unroll
    for (int rr = 0; rr < 4; ++rr) {
        float4 v = *reinterpret_cast<const float4*>(in + (size_t)(r0 + tr + rr * 16) * DMODEL + c0 + tc4);
        tile[tr + rr * 16][tc4 + 0] = v.x;
        tile[tr + rr * 16][tc4 + 1] = v.y;
        tile[tr + rr * 16][tc4 + 2] = v.z;
        tile[tr + rr * 16][tc4 + 3] = v.w;
    }
    __syncthreads();
#pragma unroll
    for (int rr = 0; rr < 4; ++rr) {
        const int c = tr + rr * 16;
        ushort4 o;
        o.x = f2bf(tile[tc4 + 0][c]);
        o.y = f2bf(tile[tc4 + 1][c]);
        o.z = f2bf(tile[tc4 + 2][c]);
        o.w = f2bf(tile[tc4 + 3][c]);
        *reinterpret_cast<ushort4*>(out + (size_t)(c0 + c) * DMODEL + r0 + tc4) = o;
    }
}

// ---------------- tiled QKV projection GEMM (m97 structure) ----------------
// C[4096][1536] = A[4096][512] x BTall[1536][512]^T, col n -> (p,h,v)
__global__ __launch_bounds__(256, 2) void proj_tiled_kernel(
    const unsigned short* __restrict__ A,
    const unsigned short* __restrict__ BTall,
    unsigned short* __restrict__ Qo,
    unsigned short* __restrict__ Ko,
    unsigned short* __restrict__ Vo) {
    __shared__ unsigned short lds[32768];  // 2 bufs x (A[128][64] + B[128][64]) swizzled
    const int tid = threadIdx.x;
    const int w = tid >> 6, l = tid & 63;
    const int l15 = l & 15, lg = l >> 4;
    const int wr = w >> 1, wc = w & 1;
    const int m0 = blockIdx.x * 128, n0 = blockIdx.y * 128;
    const int srow = l >> 3;
    const int schk = ((l & 7) ^ srow) << 3;  // pre-swizzled source chunk
    f32x4 acc[4][4] = {};
    {
        unsigned short* ab = &lds[0];
        unsigned short* bb = &lds[8192];
#pragma unroll
        for (int g = 0; g < 4; ++g) {
            gload16(A + (size_t)(m0 + w * 32 + g * 8 + srow) * DMODEL + schk,
                    ab + (w * 32 + g * 8) * 64);
            gload16(BTall + (size_t)(n0 + w * 32 + g * 8 + srow) * DMODEL + schk,
                    bb + (w * 32 + g * 8) * 64);
        }
    }
    __syncthreads();
    for (int kt = 0; kt < 8; ++kt) {
        const int b = (kt & 1) * 16384;
        if (kt + 1 < 8) {
            const int nb = ((kt + 1) & 1) * 16384;
            const int k0 = (kt + 1) * 64;
            unsigned short* ab = &lds[nb];
            unsigned short* bb = &lds[nb + 8192];
#pragma unroll
            for (int g = 0; g < 4; ++g) {
                gload16(A + (size_t)(m0 + w * 32 + g * 8 + srow) * DMODEL + k0 + schk,
                        ab + (w * 32 + g * 8) * 64);
                gload16(BTall + (size_t)(n0 + w * 32 + g * 8 + srow) * DMODEL + k0 + schk,
                        bb + (w * 32 + g * 8) * 64);
            }
        }
#pragma unroll
        for (int kk = 0; kk < 2; ++kk) {
            short8 am[4], bn[4];
#pragma unroll
            for (int mi = 0; mi < 4; ++mi) {
                const int row = wr * 64 + mi * 16 + l15;
                am[mi] = *reinterpret_cast<const short8*>(
                    &lds[b + row * 64 + ((kk * 32 + lg * 8) ^ ((row & 7) << 3))]);
            }
#pragma unroll
            for (int ni = 0; ni < 4; ++ni) {
                const int row = wc * 64 + ni * 16 + l15;
                bn[ni] = *reinterpret_cast<const short8*>(
                    &lds[b + 8192 + row * 64 + ((kk * 32 + lg * 8) ^ ((row & 7) << 3))]);
            }
#pragma unroll
            for (int mi = 0; mi < 4; ++mi)
#pragma unroll
                for (int ni = 0; ni < 4; ++ni)
                    acc[mi][ni] = __builtin_amdgcn_mfma_f32_16x16x32_bf16(am[mi], bn[ni], acc[mi][ni], 0, 0, 0);
        }
        __syncthreads();
    }
#pragma unroll
    for (int ni = 0; ni < 4; ++ni) {
        const int n = n0 + wc * 64 + ni * 16;
        const int p = n >> 9, h = (n >> 6) & 7, vb = n & 63;
        unsigned short* dst = ((p == 0) ? Qo : (p == 1) ? Ko : Vo) + (size_t)h * S_LEN * DK;
        const float sc = (p == 0) ? 0.125f : 1.0f;  // 1/sqrt(64) folded into Q
#pragma unroll
        for (int mi = 0; mi < 4; ++mi) {
            const int s = m0 + wr * 64 + mi * 16 + lg * 4;
#pragma unroll
            for (int r = 0; r < 4; ++r)
                dst[(size_t)(s + r) * DK + vb + l15] = f2bf(acc[mi][ni][r] * sc);
        }
    }
}

// ---------------- tiled output projection GEMM (x 1/Z) ----------------
__global__ __launch_bounds__(256, 2) void out_tiled_kernel(
    const unsigned short* __restrict__ A,
    const unsigned short* __restrict__ BT,
    const float* __restrict__ Z,
    float* __restrict__ Cout) {
    __shared__ unsigned short lds[32768];
    const int tid = threadIdx.x;
    const int w = tid >> 6, l = tid & 63;
    const int l15 = l & 15, lg = l >> 4;
    const int wr = w >> 1, wc = w & 1;
    const int m0 = blockIdx.x * 128, n0 = blockIdx.y * 128;
    const int srow = l >> 3;
    const int schk = ((l & 7) ^ srow) << 3;
    const float invZ = 1.0f / *Z;
    f32x4 acc[4][4] = {};
    {
        unsigned short* ab = &lds[0];
        unsigned short* bb = &lds[8192];
#pragma unroll
        for (int g = 0; g < 4; ++g) {
            gload16(A + (size_t)(m0 + w * 32 + g * 8 + srow) * DMODEL + schk,
                    ab + (w * 32 + g * 8) * 64);
            gload16(BT + (size_t)(n0 + w * 32 + g * 8 + srow) * DMODEL + schk,
                    bb + (w * 32 + g * 8) * 64);
        }
    }
    __syncthreads();
    for (int kt = 0; kt < 8; ++kt) {
        const int b = (kt & 1) * 16384;
        if (kt + 1 < 8) {
            const int nb = ((kt + 1) & 1) * 16384;
            const int k0 = (kt + 1) * 64;
            unsigned short* ab = &lds[nb];
            unsigned short* bb = &lds[nb + 8192];
#pragma unroll
            for (int g = 0; g < 4; ++g) {
                gload16(A + (size_t)(m0 + w * 32 + g * 8 + srow) * DMODEL + k0 + schk,
                        ab + (w * 32 + g * 8) * 64);
                gload16(BT + (size_t)(n0 + w * 32 + g * 8 + srow) * DMODEL + k0 + schk,
                        bb + (w * 32 + g * 8) * 64);
            }
        }
#pragma unroll
        for (int kk = 0; kk < 2; ++kk) {
            short8 am[4], bn[4];
#pragma unroll
            for (int mi = 0; mi < 4; ++mi) {
                const int row = wr * 64 + mi * 16 + l15;
                am[mi] = *reinterpret_cast<const short8*>(
                    &lds[b + row * 64 + ((kk * 32 + lg * 8) ^ ((row & 7) << 3))]);
            }
#pragma unroll
            for (int ni = 0; ni < 4; ++ni) {
                const int row = wc * 64 + ni * 16 + l15;
                bn[ni] = *reinterpret_cast<const short8*>(
                    &lds[b + 8192 + row * 64 + ((kk * 32 + lg * 8) ^ ((row & 7) << 3))]);
            }
#pragma unroll
            for (int mi = 0; mi < 4; ++mi)
#pragma unroll
                for (int ni = 0; ni < 4; ++ni)
                    acc[mi][ni] = __builtin_amdgcn_mfma_f32_16x16x32_bf16(am[mi], bn[ni], acc[mi][ni], 0, 0, 0);
        }
        __syncthreads();
    }
#pragma unroll
    for (int ni = 0; ni < 4; ++ni) {
        const int n = n0 + wc * 64 + ni * 16;
#pragma unroll
        for (int mi = 0; mi < 4; ++mi) {
            const int s = m0 + wr * 64 + mi * 16 + lg * 4;
#pragma unroll
            for (int r = 0; r < 4; ++r)
                Cout[(size_t)(s + r) * DMODEL + n + l15] = acc[mi][ni][r] * invZ;
        }
    }
}

// ---------------- V transpose: Vb[h][t][v] -> VT[h][v][t] ----------------
__global__ __launch_bounds__(256) void vt_kernel(const unsigned short* __restrict__ Vb,
                                                 unsigned short* __restrict__ VT) {
    __shared__ unsigned short tile[4096];
    int h = blockIdx.y, t0 = blockIdx.x * 64;
    const unsigned short* Vh = Vb + h * (S_LEN * DK);
    unsigned short* VTh = VT + h * (DK * S_LEN);
    int c8 = (threadIdx.x & 7) * 8, rw = threadIdx.x >> 3;
#pragma unroll
    for (int rr = 0; rr < 2; ++rr) {
        int t = rw + rr * 32;
        short8 v = *reinterpret_cast<const short8*>(Vh + (t0 + t) * DK + c8);
        *reinterpret_cast<short8*>(&tile[t * 64 + (c8 ^ ((t & 7) << 3))]) = v;
    }
    __syncthreads();
#pragma unroll
    for (int rr = 0; rr < 2; ++rr) {
        int v = rw + rr * 32;
        short8 s;
#pragma unroll
        for (int i = 0; i < 8; ++i) {
            int t = c8 + i;
            s[i] = (short)tile[t * 64 + (v ^ ((t & 7) << 3))];
        }
        *reinterpret_cast<short8*>(VTh + v * S_LEN + t0 + c8) = s;
    }
}

// ---------------- fused attention (unnormalized, split over t) ----------------
// 4 waves x 64 q = 256 q/block; t tiled by 128 (64 MFMA per barrier-pair).
// Swapped QK^T, P fully in-register (cvt_pk, k-permuted PV ds_read_b64).
__device__ __forceinline__ void make_pfrag(const f32x16& s, short8 pf[2],
                                           float& z0, float& z1) {
    float p[16];
#pragma unroll
    for (int r = 0; r < 16; ++r) p[r] = __expf(s[r]);
#pragma unroll
    for (int r = 0; r < 16; r += 2) { z0 += p[r]; z1 += p[r + 1]; }
    unsigned int c[8];
#pragma unroll
    for (int j = 0; j < 8; ++j)
        asm("v_cvt_pk_bf16_f32 %0, %1, %2" : "=v"(c[j]) : "v"(p[2 * j]), "v"(p[2 * j + 1]));
    uint4v wa = {c[0], c[1], c[2], c[3]};
    uint4v wb = {c[4], c[5], c[6], c[7]};
    pf[0] = __builtin_bit_cast(short8, wa);
    pf[1] = __builtin_bit_cast(short8, wb);
}

__global__ __launch_bounds__(256, 2) void attn_kernel(
    const unsigned short* __restrict__ Qg,
    const unsigned short* __restrict__ Kg,
    const unsigned short* __restrict__ VTg,
    float* __restrict__ Opart,
    float* __restrict__ Z) {
    __shared__ unsigned short lds[32768];  // 2 bufs x (K[128][64] + VT[64][128])
    const int tid = threadIdx.x;
    const int w = tid >> 6, l = tid & 63;
    const int l31 = l & 31, lh = l >> 5;
    const int qb = blockIdx.x, h = blockIdx.y, sp = blockIdx.z;
    const unsigned short* Qh = Qg + h * (S_LEN * DK);
    const unsigned short* Kh = Kg + h * (S_LEN * DK);
    const unsigned short* VTh = VTg + h * (DK * S_LEN);
    const int t_base = sp * (S_LEN / SPLIT);
    const int q0 = qb * 256 + w * 64;

    short8 bq[2][4];
#pragma unroll
    for (int qc = 0; qc < 2; ++qc)
#pragma unroll
        for (int ks = 0; ks < 4; ++ks)
            bq[qc][ks] = *reinterpret_cast<const short8*>(
                Qh + (q0 + qc * 32 + l31) * DK + ks * 16 + lh * 8);

    f32x16 oacc[2][2] = {};
    float z0 = 0.0f, z1 = 0.0f;

    // staging lane roles (pre-swizzled global source, linear LDS dest)
    const int kr = l >> 3;                       // K: row-in-group 0..7
    const int kc = (((l & 7) ^ kr) << 3);        // K: source chunk (row&7 == kr)
    const int vr = l >> 4;                       // VT: row-in-group 0..3

    {   // stage tile 0 -> buf 0
        unsigned short* kb = &lds[0];
        unsigned short* vbuf = &lds[8192];
#pragma unroll
        for (int g = 0; g < 4; ++g) {
            gload16(Kh + (size_t)(t_base + w * 32 + g * 8 + kr) * DK + kc,
                    kb + (w * 32 + g * 8) * 64);
            const int row = w * 16 + g * 4 + vr;
            const int chk = ((l & 15) ^ (row & 7)) << 3;
            gload16(VTh + (size_t)row * S_LEN + t_base + chk,
                    vbuf + (w * 16 + g * 4) * 128);
        }
    }
    __syncthreads();

    for (int it = 0; it < NT; ++it) {
        const int b = (it & 1) * 16384;
        if (it + 1 < NT) {
            const int nbuf = ((it + 1) & 1) * 16384;
            const int t0 = t_base + (it + 1) * TBLK;
            unsigned short* kb = &lds[nbuf];
            unsigned short* vbuf = &lds[nbuf + 8192];
#pragma unroll
            for (int g = 0; g < 4; ++g) {
                gload16(Kh + (size_t)(t0 + w * 32 + g * 8 + kr) * DK + kc,
                        kb + (w * 32 + g * 8) * 64);
                const int row = w * 16 + g * 4 + vr;
                const int chk = ((l & 15) ^ (row & 7)) << 3;
                gload16(VTh + (size_t)row * S_LEN + t0 + chk,
                        vbuf + (w * 16 + g * 4) * 128);
            }
        }
#pragma unroll
        for (int tc = 0; tc < 4; ++tc) {
            f32x16 s0 = {}, s1 = {};
            const int tA = tc * 32 + l31;
#pragma unroll
            for (int ks = 0; ks < 4; ++ks) {
                short8 ka = *reinterpret_cast<const short8*>(
                    &lds[b + tA * 64 + ((ks * 16 + lh * 8) ^ ((tA & 7) << 3))]);
                s0 = __builtin_amdgcn_mfma_f32_32x32x16_bf16(ka, bq[0][ks], s0, 0, 0, 0);
                s1 = __builtin_amdgcn_mfma_f32_32x32x16_bf16(ka, bq[1][ks], s1, 0, 0, 0);
            }
            short8 pf0[2], pf1[2];
            make_pfrag(s0, pf0, z0, z1);
            make_pfrag(s1, pf1, z0, z1);
#pragma unroll
            for (int sub = 0; sub < 2; ++sub) {
#pragma unroll
                for (int vc = 0; vc < 2; ++vc) {
                    const int vx = l31 & 7;
                    const int cc = tc * 4 + sub * 2;
                    const int base = b + 16384 - 8192 + (vc * 32 + l31) * 128;  // VT at b+8192
                    unsigned long long d0 = *reinterpret_cast<const unsigned long long*>(
                        &lds[b + 8192 + (vc * 32 + l31) * 128 + ((cc ^ vx) << 3) + lh * 4]);
                    unsigned long long d1 = *reinterpret_cast<const unsigned long long*>(
                        &lds[b + 8192 + (vc * 32 + l31) * 128 + (((cc + 1) ^ vx) << 3) + lh * 4]);
                    (void)base;
                    ull2 dd = {d0, d1};
                    short8 bv = __builtin_bit_cast(short8, dd);
                    oacc[0][vc] = __builtin_amdgcn_mfma_f32_32x32x16_bf16(pf0[sub], bv, oacc[0][vc], 0, 0, 0);
                    oacc[1][vc] = __builtin_amdgcn_mfma_f32_32x32x16_bf16(pf1[sub], bv, oacc[1][vc], 0, 0, 0);
                }
            }
        }
        __syncthreads();
    }
    float* Op = Opart + ((size_t)(sp * NHEAD + h) * S_LEN + q0) * DK;
#pragma unroll
    for (int qc = 0; qc < 2; ++qc)
#pragma unroll
        for (int vc = 0; vc < 2; ++vc)
#pragma unroll
            for (int reg = 0; reg < 16; ++reg) {
                int q = qc * 32 + (reg & 3) + 8 * (reg >> 2) + 4 * lh;
                Op[(size_t)q * DK + vc * 32 + l31] = oacc[qc][vc][reg];
            }
    float zloc = z0 + z1;
#pragma unroll
    for (int off = 32; off > 0; off >>= 1) zloc += __shfl_xor(zloc, off, 64);
    if (l == 0) atomicAdd(Z, zloc);
}

// ---------------- split reduction: sum partials -> bf16 concat ----------------
__global__ __launch_bounds__(256) void reduce_o_kernel(
    const float* __restrict__ Opart, unsigned short* __restrict__ cc) {
    const int HSV = NHEAD * S_LEN * DK;
    int i = blockIdx.x * blockDim.x + threadIdx.x;
    if (i * 4 >= HSV) return;
    f32x4 s = {};
#pragma unroll
    for (int sp = 0; sp < SPLIT; ++sp) {
        f32x4 v = *reinterpret_cast<const f32x4*>(&Opart[(size_t)sp * HSV + i * 4]);
        s += v;
    }
    int e = i * 4;
    int h = e / (S_LEN * DK);
    int rem = e - h * (S_LEN * DK);
    int srow = rem / DK;
    int v = rem - srow * DK;
    ushort4 o4;
    o4.x = f2bf(s[0]); o4.y = f2bf(s[1]); o4.z = f2bf(s[2]); o4.w = f2bf(s[3]);
    *reinterpret_cast<ushort4*>(&cc[srow * DMODEL + h * DK + v]) = o4;
}

// ---------------- launcher ----------------

extern "C" void kernel_launch(void* const* d_in, const int* in_sizes, int n_in,
                              void* d_out, int out_size, void* d_ws, size_t ws_size,
                              hipStream_t stream) {
    const float* emb = (const float*)d_in[0];
    const float* wq = (const float*)d_in[1];
    const float* wk = (const float*)d_in[2];
    const float* wv = (const float*)d_in[3];
    const float* wo = (const float*)d_in[4];
    float* out = (float*)d_out;
    char* ws = (char*)d_ws;
    unsigned short* embB = (unsigned short*)(ws);             // 4 MB (reused as VT)
    unsigned short* wqT  = (unsigned short*)(ws + 4194304);   // contiguous 3 x 512 KB
    unsigned short* wkT  = (unsigned short*)(ws + 4718592);
    unsigned short* wvT  = (unsigned short*)(ws + 5242880);
    unsigned short* woT  = (unsigned short*)(ws + 5767168);
    unsigned short* Qb   = (unsigned short*)(ws + 6291456);   // 4 MB each
    unsigned short* Kb   = (unsigned short*)(ws + 10485760);
    unsigned short* Vb   = (unsigned short*)(ws + 14680064);
    unsigned short* cc   = (unsigned short*)(ws + 18874368);  // 4 MB
    float* Z             = (float*)(ws + 23068672);
    float* Opart         = (float*)(ws + 23072768);           // 32 MB
    unsigned short* VT   = embB;  // embB dead after proj

    cast_bf16_kernel<<<2048, 256, 0, stream>>>(emb, embB, 524288, Z);
    transpose_qkv_kernel<<<dim3(8, 24), 256, 0, stream>>>(wq, wk, wv, wqT, wkT, wvT);
    transpose_wo_kernel<<<dim3(8, 8), 256, 0, stream>>>(wo, woT);
    proj_tiled_kernel<<<dim3(32, 12), 256, 0, stream>>>(embB, wqT, Qb, Kb, Vb);
    vt_kernel<<<dim3(64, 8), 256, 0, stream>>>(Vb, VT);
    attn_kernel<<<dim3(16, 8, SPLIT), 256, 0, stream>>>(Qb, Kb, VT, Opart, Z);
    reduce_o_kernel<<<2048, 256, 0, stream>>>(Opart, cc);
    out_tiled_kernel<<<dim3(32, 4), 256, 0, stream>>>(cc, woT, Z, out);
}